// Round 9
// baseline (162.569 us; speedup 1.0000x reference)
//
#include <hip/hip_runtime.h>
#include <math.h>

using u8  = unsigned char;
using u32 = unsigned int;
using u64 = unsigned long long;

typedef short short8 __attribute__((ext_vector_type(8)));
typedef float f32x4  __attribute__((ext_vector_type(4)));

#define MC 2048
#define NC 2048
#define DF 256
#define NFULL 50000
#define NBACK 30000
#define KCORR 4096
#define MAXPTS 256
#define NN_CHUNK 196     // 256 chunks * 196 = 50176 >= 50000
#define BM_WORDS_I 1568

// ---------------- workspace layout ----------------
constexpr size_t OFF_ROWP = 0;                                // 64*2048 float4 = 2 MB
constexpr size_t OFF_COLP = (size_t)2 * 1024 * 1024;          // 32*2048 float4 = 1 MB
constexpr size_t OFF_GTB  = (size_t)3 * 1024 * 1024;          // 2048*64 u32 = 512 KB (bitfield)
constexpr size_t OFF_NN   = OFF_GTB + (size_t)512 * 1024;     // 4096 u64 = 32 KB
constexpr size_t OFF_CAND = OFF_NN + 4096 * 8;                // 4096 u64 = 32 KB
constexpr size_t OFF_ACC  = OFF_CAND + 4096 * 8;              // 8 f32
constexpr size_t OFF_CNT  = OFF_ACC + 256;                    // cnt, tickets
constexpr size_t OFF_BM   = OFF_CNT + 256;                    // 2*1568 u32 = 12.5 KB
constexpr size_t OFF_HASH = OFF_BM + 3200 * 4;                // 8192 u64 = 64 KB
constexpr size_t OFF_P4R  = OFF_HASH + 8192 * 8;              // 51200 float4 = 800 KB
constexpr size_t OFF_P4S  = OFF_P4R + (size_t)51200 * 16;     // 51200 float4 = 800 KB

// ---------------- init: zero state + build float4(x,y,z,|p|^2) arrays ----------------
__global__ __launch_bounds__(256) void k_init(uint4* __restrict__ gtb4, u64* __restrict__ nn,
                                              float* __restrict__ acc, u64* __restrict__ hash,
                                              u32* __restrict__ cnt, u32* __restrict__ bm,
                                              const float* __restrict__ pr, const float* __restrict__ ps,
                                              float4* __restrict__ p4r, float4* __restrict__ p4s) {
    int e = blockIdx.x * 256 + threadIdx.x;   // 0..131071
    if (e < 32768) gtb4[e] = make_uint4(0u, 0u, 0u, 0u);
    if (e < 8192) hash[e] = 0ull;
    if (e < 4096) nn[e] = ~0ull;
    if (e < 2 * BM_WORDS_I) bm[e] = 0u;
    if (e < 8) acc[e] = 0.f;
    if (e < 4) cnt[e] = 0u;
    if (e < NFULL) {
        float x = pr[e*3], y = pr[e*3+1], z = pr[e*3+2];
        p4r[e] = make_float4(x, y, z, x*x + y*y + z*z);
    }
    int j = e - 65536;
    if (j >= 0 && j < NFULL) {
        float x = ps[j*3], y = ps[j*3+1], z = ps[j*3+2];
        p4s[j] = make_float4(x, y, z, x*x + y*y + z*z);
    }
}

// ---------------- NN argmin: scalar-broadcast candidates, no LDS ----------------
// grid: x = (4 i-blocks) | (256 chunks << 2), y = side. 2048 blocks, 8 waves/SIMD.
// Candidates read with a block-uniform index from precomputed float4 -> s_load
// broadcast (no LDS pipe, no staging, no __syncthreads). Eval = 3 fma + cmp +
// 2 cndmask = 6 VALU. cn omitted in-loop (argmin-invariant), re-added for the
// packed cross-block atomicMin merge.
// Prologue: first 235 blocks also build the back-index bitmaps (k_bm folded in).
__global__ __launch_bounds__(256) void k_nn(
        const float4* __restrict__ f4r, const float4* __restrict__ f4s,
        const float* __restrict__ cr, const float* __restrict__ cs,
        const int* __restrict__ rbi, const int* __restrict__ sbi,
        u32* __restrict__ bm, u64* __restrict__ nn) {
    const int side = blockIdx.y;
    const int t = threadIdx.x;

    // folded k_bm: 235*256 = 60160 >= 60000 entries
    int gb = side * 1024 + blockIdx.x;
    if (gb < 235) {
        int e = gb * 256 + t;
        if (e < 2 * NBACK) {
            int s2 = e < NBACK ? 0 : 1;
            int v = s2 ? sbi[e - NBACK] : rbi[e];
            atomicOr(&bm[s2 * BM_WORDS_I + (v >> 5)], 1u << (v & 31));
        }
    }

    const float4* full4 = side ? f4s : f4r;
    const float* corr  = side ? cs : cr;
    const int ib = blockIdx.x & 3, ch = blockIdx.x >> 2;

    float ax[2], ay[2], az[2], bd[2];
    u32 bj[2];
    #pragma unroll
    for (int q = 0; q < 2; ++q) {
        int i = ib * 512 + q * 256 + t;
        float cx = corr[i*3], cy = corr[i*3+1], cz = corr[i*3+2];
        ax[q] = -2.f*cx; ay[q] = -2.f*cy; az[q] = -2.f*cz;
        bd[q] = 3.4e38f; bj[q] = 0u;
    }

    const int j0 = ch * NN_CHUNK;
    const int j1 = min(j0 + NN_CHUNK, NFULL);
    #pragma unroll 4
    for (int j = j0; j < j1; ++j) {
        float4 p = full4[j];             // block-uniform -> scalar/broadcast load
        #pragma unroll
        for (int q = 0; q < 2; ++q) {
            float d = fmaf(ax[q], p.x, fmaf(ay[q], p.y, fmaf(az[q], p.z, p.w)));
            if (d < bd[q]) { bd[q] = d; bj[q] = (u32)j; }
        }
    }

    #pragma unroll
    for (int q = 0; q < 2; ++q) {
        int i = ib * 512 + q * 256 + t;
        float cn = 0.25f * fmaf(ax[q], ax[q], fmaf(ay[q], ay[q], az[q]*az[q]));
        float bf = bd[q] + cn;
        u32 db = __float_as_uint(bf);
        db = (db & 0x80000000u) ? ~db : (db | 0x80000000u);
        atomicMin(&nn[side * 2048 + i], ((u64)db << 32) | bj[q]);
    }
}

// ---------------- fused mask + loss2 + scat1 + (ticket) scat2 ----------------
// 16 blocks x 256. Each block recomputes the full 4096-entry mask into LDS.
// Block b scatters gt entries [b*256, b*256+256). Masked flag packed into hash
// value. Last-arriving block collects candidates from the hash (scat2).
__global__ __launch_bounds__(256) void k_msc(
        const u64* __restrict__ nn, const u32* __restrict__ bm,
        const float* __restrict__ spm, const int* __restrict__ gti,
        const float* __restrict__ gtv,
        u32* __restrict__ gtb, u64* __restrict__ hash,
        u64* __restrict__ cand, u32* __restrict__ cnt, float* __restrict__ acc) {
    __shared__ u8 smask[4096];
    __shared__ float red[4];
    __shared__ u32 s_tic;
    const int t = threadIdx.x;
    float c = 0.f;
    for (int e = t; e < 4096; e += 256) {
        int side = e >> 11;
        u32 j = (u32)(nn[e] & 0xFFFFFFFFull);
        u32 bit = (bm[side * BM_WORDS_I + (j >> 5)] >> (j & 31)) & 1u;
        smask[e] = (u8)bit;
        if (blockIdx.x == 0) c += fabsf((1.f - spm[e]) - (float)bit);
    }
    if (blockIdx.x == 0) {
        for (int o = 32; o; o >>= 1) c += __shfl_xor(c, o);
        if ((t & 63) == 0) red[t >> 6] = c;
    }
    __syncthreads();
    if (blockIdx.x == 0 && t == 0) acc[2] = red[0] + red[1] + red[2] + red[3];

    // scat1 slice: one k per thread
    int k = blockIdx.x * 256 + t;
    int xi = gti[2*k], yi = gti[2*k+1];
    u32 cell = (u32)(xi * 2048 + yi);
    u32 masked = (smask[xi] && smask[2048 + yi]) ? 1u : 0u;
    if (masked) atomicOr(&gtb[xi * 64 + (yi >> 5)], 1u << (yi & 31));
    u64 val = ((u64)(cell + 1) << 13) | ((u64)masked << 12) | (u32)k;
    u32 h = (cell * 2654435761u) >> 19;
    while (true) {
        u64 cur = hash[h];
        if (cur == 0ull) cur = atomicCAS(&hash[h], 0ull, val);
        if (cur == 0ull) break;                                   // inserted
        if ((cur >> 13) == (u64)(cell + 1)) { atomicMax(&hash[h], val); break; }
        h = (h + 1) & 8191;
    }

    // ticket: last block performs scat2 (candidate collection)
    __threadfence();
    __syncthreads();
    if (t == 0) s_tic = atomicAdd(&cnt[2], 1u);
    __syncthreads();
    if (s_tic == 15u) {
        __threadfence();
        for (int e = t; e < 8192; e += 256) {
            u64 s = atomicOr(&hash[e], 0ull);    // coherent read of other blocks' writes
            if (s == 0ull) continue;
            if (!((s >> 12) & 1ull)) continue;   // masked flag
            u32 cl = (u32)(s >> 13) - 1u;
            u32 kk = (u32)(s & 0xFFFull);
            u32 vb = __float_as_uint(gtv[kk]);   // overlaps >= 0 -> bits monotonic
            u32 idx = atomicAdd(&cnt[0], 1u);
            cand[idx] = ((u64)vb << 22) | (u32)(0x3FFFFF - cl);
        }
    }
}

// ---------------- top-256 cap, spread over 16 blocks ----------------
__global__ __launch_bounds__(256) void k_top(const u64* __restrict__ cand,
                                             const u32* __restrict__ cnt,
                                             u32* __restrict__ gtb) {
    const int n = (int)cnt[0];
    if (n <= MAXPTS) return;
    if (blockIdx.x * 256 >= n) return;
    __shared__ u64 keys[4096];
    const int t = threadIdx.x;
    for (int e = t; e < n; e += 256) keys[e] = cand[e];
    __syncthreads();
    int c = blockIdx.x * 256 + t;
    if (c >= n) return;
    u64 me = keys[c];
    int rank = 0;
    #pragma unroll 4
    for (int j = 0; j < n; ++j) rank += (keys[j] > me);
    if (rank >= MAXPTS) {
        u32 cell = 0x3FFFFFu - (u32)(me & 0x3FFFFFull);
        int row = cell >> 11, col = cell & 2047;
        atomicAnd(&gtb[row * 64 + (col >> 5)], ~(1u << (col & 31)));
    }
}

// ---------------- circle-loss terms ----------------
__device__ __forceinline__ void circle_terms(float d, bool g, float& lp, float& ln) {
    if (g) { float a = d - 0.1f; lp = a > 0.f ? 24.f*a*a : 0.f; ln = 0.f; }
    else   { float b = 1.4f - d; ln = b > 0.f ? 24.f*b*b : 0.f; lp = 0.f; }
}

__device__ __forceinline__ float softplus_(float x) {
    return fmaxf(x, 0.f) + log1pf(expf(-fabsf(x)));
}

// ---------------- fused MFMA bf16 GEMM + laplace + row/col LSE partials ----------------
__global__ __launch_bounds__(256) void k_gemm(
        const float* __restrict__ A, const float* __restrict__ B,
        const float* __restrict__ spm, const u32* __restrict__ gtb,
        float4* __restrict__ rowp, float4* __restrict__ colp) {
    __shared__ __align__(16) short As[16384];   // 32 KB
    __shared__ __align__(16) short Bs[8192];    // 16 KB
    __shared__ u32 gtw[256];                    // 1 KB: 128 rows x 2 words
    const int t = threadIdx.x;
    const int l = t & 63, wid = t >> 6;
    const int wm = wid >> 1, wn = wid & 1;
    const int i0 = blockIdx.y * 128, j0 = blockIdx.x * 64;

    // stage gt bits for this 128x64 tile (1 u32 per thread, broadcast reads later)
    gtw[t] = gtb[(size_t)(i0 + (t >> 1)) * 64 + (j0 >> 5) + (t & 1)];

    f32x4 acc[4][2] = {};

    for (int ks = 0; ks < 2; ++ks) {
        __syncthreads();
        #pragma unroll
        for (int it = 0; it < 12; ++it) {
            int sl = it * 256 + t;                 // 0..3071 slots of 16B
            int c = sl & 63, q = c >> 4, r15 = c & 15;
            const float* src;
            short* dst;
            int kf;
            if (it < 8) {                          // A: slots 0..2047
                int frag = sl >> 6;                // mf(8) x kf(4)
                kf = frag & 3;
                int row = (frag >> 2) * 16 + r15;
                src = A + (size_t)(i0 + row) * 256;
                dst = &As[sl * 8];
            } else {                               // B: slots 2048..3071
                int sl2 = sl - 2048;
                int frag = sl2 >> 6;               // nf(4) x kf(4)
                kf = frag & 3;
                int row = (frag >> 2) * 16 + r15;
                src = B + (size_t)(j0 + row) * 256;
                dst = &Bs[sl2 * 8];
            }
            int col = ks * 128 + kf * 32 + q * 8;
            float4 v0 = *(const float4*)(src + col);
            float4 v1 = *(const float4*)(src + col + 4);
            u32 w0 = __builtin_amdgcn_perm(__float_as_uint(v0.y), __float_as_uint(v0.x), 0x07060302u);
            u32 w1 = __builtin_amdgcn_perm(__float_as_uint(v0.w), __float_as_uint(v0.z), 0x07060302u);
            u32 w2 = __builtin_amdgcn_perm(__float_as_uint(v1.y), __float_as_uint(v1.x), 0x07060302u);
            u32 w3 = __builtin_amdgcn_perm(__float_as_uint(v1.w), __float_as_uint(v1.z), 0x07060302u);
            *(uint4*)dst = make_uint4(w0, w1, w2, w3);
        }
        __syncthreads();

        #pragma unroll
        for (int kf = 0; kf < 4; ++kf) {
            short8 a[4], b[2];
            #pragma unroll
            for (int mi = 0; mi < 4; ++mi)
                a[mi] = *(const short8*)&As[(((wm*4 + mi)*4 + kf) << 9) + l*8];
            #pragma unroll
            for (int ni = 0; ni < 2; ++ni)
                b[ni] = *(const short8*)&Bs[(((wn*2 + ni)*4 + kf) << 9) + l*8];
            #pragma unroll
            for (int mi = 0; mi < 4; ++mi)
                #pragma unroll
                for (int ni = 0; ni < 2; ++ni)
                    acc[mi][ni] = __builtin_amdgcn_mfma_f32_16x16x32_bf16(
                        a[mi], b[ni], acc[mi][ni], 0, 0, 0);
        }
    }

    // ---- epilogue ----
    // C/D layout: col = lane&15, row = (lane>>4)*4 + reg  [m89-verified]
    const int cq = l >> 4, cr = l & 15;
    const int rows0 = i0 + wm * 64, cols0 = j0 + wn * 32;

    float vmj[2];
    #pragma unroll
    for (int ni = 0; ni < 2; ++ni) vmj[ni] = 1.f - spm[2048 + cols0 + ni*16 + cr];
    float vmi[4][4];
    #pragma unroll
    for (int mi = 0; mi < 4; ++mi)
        #pragma unroll
        for (int rr = 0; rr < 4; ++rr)
            vmi[mi][rr] = 1.f - spm[rows0 + mi*16 + cq*4 + rr];

    // d in place + gt bitmask from LDS bits (bit mi*8 + ni*4 + rr)
    u32 gmask = 0;
    #pragma unroll
    for (int mi = 0; mi < 4; ++mi)
        #pragma unroll
        for (int rr = 0; rr < 4; ++rr) {
            u32 w = gtw[(wm*64 + mi*16 + cq*4 + rr) * 2 + wn];
            #pragma unroll
            for (int ni = 0; ni < 2; ++ni)
                if ((w >> (ni*16 + cr)) & 1u) gmask |= 1u << (mi*8 + ni*4 + rr);
        }
    #pragma unroll
    for (int mi = 0; mi < 4; ++mi)
        #pragma unroll
        for (int ni = 0; ni < 2; ++ni)
            #pragma unroll
            for (int rr = 0; rr < 4; ++rr) {
                float s  = acc[mi][ni][rr];
                float fs = fmaxf(2.f - 2.f*s, 0.f);
                acc[mi][ni][rr] = sqrtf(fs) * expf(0.5f * vmi[mi][rr] * vmj[ni]);
            }

    const int jt2 = blockIdx.x * 2 + wn;   // 0..63
    const int it2 = blockIdx.y * 2 + wm;   // 0..31

    // row-LSE: per row (mi,cq,rr), over ni(2) x 16 lanes. two-phase.
    #pragma unroll
    for (int mi = 0; mi < 4; ++mi)
        #pragma unroll
        for (int rr = 0; rr < 4; ++rr) {
            float lp0, ln0, lp1, ln1;
            circle_terms(acc[mi][0][rr], (gmask >> (mi*8 + rr)) & 1, lp0, ln0);
            circle_terms(acc[mi][1][rr], (gmask >> (mi*8 + 4 + rr)) & 1, lp1, ln1);
            float mp = fmaxf(lp0, lp1), mn = fmaxf(ln0, ln1);
            #pragma unroll
            for (int o = 1; o < 16; o <<= 1) {
                mp = fmaxf(mp, __shfl_xor(mp, o));
                mn = fmaxf(mn, __shfl_xor(mn, o));
            }
            float sp = expf(lp0 - mp) + expf(lp1 - mp);
            float sn = expf(ln0 - mn) + expf(ln1 - mn);
            #pragma unroll
            for (int o = 1; o < 16; o <<= 1) {
                sp += __shfl_xor(sp, o);
                sn += __shfl_xor(sn, o);
            }
            if (cr == mi*4 + rr) {
                int row = rows0 + mi*16 + cq*4 + rr;
                rowp[(size_t)jt2 * 2048 + row] = make_float4(mp, sp, mn, sn);
            }
        }

    // col-LSE: per col (ni,cr), over mi(4) x rr(4) in-lane, then cq bfly.
    #pragma unroll
    for (int ni = 0; ni < 2; ++ni) {
        float lp[16], ln[16];
        #pragma unroll
        for (int mi = 0; mi < 4; ++mi)
            #pragma unroll
            for (int rr = 0; rr < 4; ++rr)
                circle_terms(acc[mi][ni][rr], (gmask >> (mi*8 + ni*4 + rr)) & 1,
                             lp[mi*4+rr], ln[mi*4+rr]);
        float mp = lp[0], mn = ln[0];
        #pragma unroll
        for (int e = 1; e < 16; ++e) { mp = fmaxf(mp, lp[e]); mn = fmaxf(mn, ln[e]); }
        #pragma unroll
        for (int o = 16; o < 64; o <<= 1) {
            mp = fmaxf(mp, __shfl_xor(mp, o));
            mn = fmaxf(mn, __shfl_xor(mn, o));
        }
        float sp = 0.f, sn = 0.f;
        #pragma unroll
        for (int e = 0; e < 16; ++e) { sp += expf(lp[e] - mp); sn += expf(ln[e] - mn); }
        #pragma unroll
        for (int o = 16; o < 64; o <<= 1) {
            sp += __shfl_xor(sp, o);
            sn += __shfl_xor(sn, o);
        }
        if (cq == 0) {
            int col = cols0 + ni*16 + cr;
            colp[(size_t)it2 * 2048 + col] = make_float4(mp, sp, mn, sn);
        }
    }
}

// ---------------- merge partials + finalize (last-block ticket) ----------------
__global__ __launch_bounds__(256) void k_merge(const float4* __restrict__ rowp,
                                               const float4* __restrict__ colp,
                                               float* __restrict__ acc,
                                               u32* __restrict__ cnt,
                                               float* __restrict__ out) {
    const int t = threadIdx.x;
    const int bx = blockIdx.x;  // 0..15: 0-7 rows, 8-15 cols
    float Mp = -1e30f, Sp = 0.f, Mn = -1e30f, Sn = 0.f;
    if (bx < 8) {
        int row = bx * 256 + t;
        for (int jt = 0; jt < 64; ++jt) {
            float4 p = rowp[(size_t)jt * 2048 + row];
            float nm = fmaxf(Mp, p.x); Sp = Sp*expf(Mp-nm) + p.y*expf(p.x-nm); Mp = nm;
            nm = fmaxf(Mn, p.z); Sn = Sn*expf(Mn-nm) + p.w*expf(p.z-nm); Mn = nm;
        }
    } else {
        int col = (bx - 8) * 256 + t;
        for (int it = 0; it < 32; ++it) {
            float4 p = colp[(size_t)it * 2048 + col];
            float nm = fmaxf(Mp, p.x); Sp = Sp*expf(Mp-nm) + p.y*expf(p.x-nm); Mp = nm;
            nm = fmaxf(Mn, p.z); Sn = Sn*expf(Mn-nm) + p.w*expf(p.z-nm); Mn = nm;
        }
    }
    float x = (Mp + logf(Sp)) + (Mn + logf(Sn));
    float lv = softplus_(x) * (1.f / 24.f);
    for (int o = 32; o; o >>= 1) lv += __shfl_xor(lv, o);
    __shared__ float wsum[4];
    __shared__ u32 tic;
    if ((t & 63) == 0) wsum[t >> 6] = lv;
    __syncthreads();
    if (t == 0) {
        atomicAdd(&acc[bx < 8 ? 0 : 1], wsum[0] + wsum[1] + wsum[2] + wsum[3]);
        __threadfence();
        tic = atomicAdd(&cnt[1], 1u);
    }
    __syncthreads();
    if (t == 0 && tic == 15u) {
        __threadfence();
        float a0 = atomicAdd(&acc[0], 0.f);
        float a1 = atomicAdd(&acc[1], 0.f);
        float a2 = atomicAdd(&acc[2], 0.f);
        float l1 = (a0 + a1) * (0.5f / 2048.f);
        float l2 = a2 * (1.f / 4096.f);
        out[0] = l1 + l2; out[1] = l1; out[2] = l2;
    }
}

extern "C" void kernel_launch(void* const* d_in, const int* in_sizes, int n_in,
                              void* d_out, int out_size, void* d_ws, size_t ws_size,
                              hipStream_t stream) {
    (void)in_sizes; (void)n_in; (void)out_size; (void)ws_size;
    const float* ref_points = (const float*)d_in[0];
    const float* src_points = (const float*)d_in[1];
    const float* ref_c      = (const float*)d_in[2];
    const float* src_c      = (const float*)d_in[3];
    const float* ref_f      = (const float*)d_in[4];
    const float* src_f      = (const float*)d_in[5];
    const int*   gti        = (const int*)d_in[6];
    const float* gtv        = (const float*)d_in[7];
    const float* spm        = (const float*)d_in[8];
    const int*   rbi        = (const int*)d_in[9];
    const int*   sbi        = (const int*)d_in[10];

    char* ws = (char*)d_ws;
    float4* rowp = (float4*)(ws + OFF_ROWP);
    float4* colp = (float4*)(ws + OFF_COLP);
    u32*   gtb  = (u32*)  (ws + OFF_GTB);
    u64*   nn   = (u64*)  (ws + OFF_NN);
    u64*   cand = (u64*)  (ws + OFF_CAND);
    float* acc  = (float*)(ws + OFF_ACC);
    u32*   cnt  = (u32*)  (ws + OFF_CNT);
    u32*   bm   = (u32*)  (ws + OFF_BM);
    u64*   hash = (u64*)  (ws + OFF_HASH);
    float4* p4r = (float4*)(ws + OFF_P4R);
    float4* p4s = (float4*)(ws + OFF_P4S);

    k_init <<<512, 256, 0, stream>>>((uint4*)gtb, nn, acc, hash, cnt, bm,
                                     ref_points, src_points, p4r, p4s);
    k_nn   <<<dim3(1024, 2), 256, 0, stream>>>(p4r, p4s, ref_c, src_c, rbi, sbi, bm, nn);
    k_msc  <<<16, 256, 0, stream>>>(nn, bm, spm, gti, gtv, gtb, hash, cand, cnt, acc);
    k_top  <<<16, 256, 0, stream>>>(cand, cnt, gtb);
    k_gemm <<<dim3(32, 16), 256, 0, stream>>>(ref_f, src_f, spm, gtb, rowp, colp);
    k_merge<<<16, 256, 0, stream>>>(rowp, colp, acc, cnt, (float*)d_out);
}

// Round 10
// 120.286 us; speedup vs baseline: 1.3515x; 1.3515x over previous
//
#include <hip/hip_runtime.h>
#include <math.h>

using u8  = unsigned char;
using u32 = unsigned int;
using u64 = unsigned long long;

typedef short short8 __attribute__((ext_vector_type(8)));
typedef float f32x4  __attribute__((ext_vector_type(4)));

#define MC 2048
#define NC 2048
#define DF 256
#define NFULL 50000
#define NBACK 30000
#define KCORR 4096
#define MAXPTS 256
#define NN_CHUNK 391   // 128 chunks * 391 = 50048 >= 50000; staged 392 (overlap 1)
#define BM_WORDS_I 1568

// ---------------- workspace layout ----------------
constexpr size_t OFF_ROWP = 0;                                // 64*2048 float4 = 2 MB
constexpr size_t OFF_COLP = (size_t)2 * 1024 * 1024;          // 32*2048 float4 = 1 MB
constexpr size_t OFF_GTB  = (size_t)3 * 1024 * 1024;          // 2048*64 u32 = 512 KB (bitfield)
constexpr size_t OFF_NN   = OFF_GTB + (size_t)512 * 1024;     // 4096 u64 = 32 KB
constexpr size_t OFF_CAND = OFF_NN + 4096 * 8;                // 4096 u64 = 32 KB
constexpr size_t OFF_ACC  = OFF_CAND + 4096 * 8;              // 8 f32
constexpr size_t OFF_CNT  = OFF_ACC + 256;                    // cnt, ticket
constexpr size_t OFF_BM   = OFF_CNT + 256;                    // 2*1568 u32 = 12.5 KB
constexpr size_t OFF_HASH = OFF_BM + 3200 * 4;                // 8192 u64 = 64 KB

// ---------------- init: zero gtb/hash/nn/bm/acc/cnt ----------------
__global__ __launch_bounds__(256) void k_init(uint4* __restrict__ gtb4, u64* __restrict__ nn,
                                              float* __restrict__ acc, u64* __restrict__ hash,
                                              u32* __restrict__ cnt, u32* __restrict__ bm) {
    int e = blockIdx.x * 256 + threadIdx.x;   // 0..32767
    gtb4[e] = make_uint4(0u, 0u, 0u, 0u);
    if (e < 8192) hash[e] = 0ull;
    if (e < 4096) nn[e] = ~0ull;
    if (e < 2 * BM_WORDS_I) bm[e] = 0u;
    if (e < 8) acc[e] = 0.f;
    if (e < 2) cnt[e] = 0u;
}

// ---------------- back-index bitmaps (wide, global) ----------------
__global__ void k_bm(const int* __restrict__ rb, const int* __restrict__ sb, u32* __restrict__ bm) {
    int e = blockIdx.x * 256 + threadIdx.x;
    if (e < NBACK) {
        int v = rb[e];
        atomicOr(&bm[v >> 5], 1u << (v & 31));
    } else if (e < 2*NBACK) {
        int v = sb[e - NBACK];
        atomicOr(&bm[BM_WORDS_I + (v >> 5)], 1u << (v & 31));
    }
}

// ---------------- NN argmin: LDS-staged, group-of-4 min + index rescan ----------------
// grid: x = (4 i-blocks) | (128 chunks << 2), y = side. block 256, IPT=2.
// Inner loop tracks only the min distance (fmin tree) + winning group id:
// 18 VALU per 4 candidates per point vs 24 for per-eval index tracking.
// Exact argmin index recovered by rescanning the winning group (bit-identical
// fma chain -> == match; strict < update + in-order rescan = first-index tie-break).
// Chunks overlap by 1 candidate (slot 391); duplicate j's merge idempotently.
__global__ __launch_bounds__(256) void k_nn(
        const float* __restrict__ fr, const float* __restrict__ fs,
        const float* __restrict__ cr, const float* __restrict__ cs,
        u64* __restrict__ nn) {
    const int side = blockIdx.y;
    const float* full = side ? fs : fr;
    const float* corr = side ? cs : cr;
    const int ib = blockIdx.x & 3, ch = blockIdx.x >> 2;
    const int t = threadIdx.x;

    __shared__ float4 s4[392];
    const int j0 = ch * NN_CHUNK;
    for (int e = t; e < 392; e += 256) {
        int j = j0 + e;
        float4 v;
        if (j < NFULL) {
            float x = full[j*3], y = full[j*3+1], z = full[j*3+2];
            v = make_float4(x, y, z, x*x + y*y + z*z);
        } else {
            v = make_float4(0.f, 0.f, 0.f, 3.0e38f);   // sentinel: never wins
        }
        s4[e] = v;
    }

    float ax[2], ay[2], az[2], bd[2];
    int bg[2];
    #pragma unroll
    for (int q = 0; q < 2; ++q) {
        int i = ib * 512 + q * 256 + t;
        float cx = corr[i*3], cy = corr[i*3+1], cz = corr[i*3+2];
        ax[q] = -2.f*cx; ay[q] = -2.f*cy; az[q] = -2.f*cz;
        bd[q] = 3.4e38f; bg[q] = 0;
    }
    __syncthreads();

    #pragma unroll 2
    for (int g = 0; g < 98; ++g) {
        float4 p0 = s4[g*4+0], p1 = s4[g*4+1], p2 = s4[g*4+2], p3 = s4[g*4+3];
        #pragma unroll
        for (int q = 0; q < 2; ++q) {
            float d0 = fmaf(ax[q], p0.x, fmaf(ay[q], p0.y, fmaf(az[q], p0.z, p0.w)));
            float d1 = fmaf(ax[q], p1.x, fmaf(ay[q], p1.y, fmaf(az[q], p1.z, p1.w)));
            float d2 = fmaf(ax[q], p2.x, fmaf(ay[q], p2.y, fmaf(az[q], p2.z, p2.w)));
            float d3 = fmaf(ax[q], p3.x, fmaf(ay[q], p3.y, fmaf(az[q], p3.z, p3.w)));
            float gm = fminf(fminf(d0, d1), fminf(d2, d3));
            bool win = gm < bd[q];
            bd[q] = fminf(bd[q], gm);
            bg[q] = win ? g : bg[q];
        }
    }

    #pragma unroll
    for (int q = 0; q < 2; ++q) {
        // rescan winning group for the exact (first) index
        int base = bg[q] * 4;
        u32 bj = (u32)(j0 + base);
        bool found = false;
        #pragma unroll
        for (int u = 0; u < 4; ++u) {
            float4 p = s4[base + u];
            float d = fmaf(ax[q], p.x, fmaf(ay[q], p.y, fmaf(az[q], p.z, p.w)));
            if (!found && d == bd[q]) { bj = (u32)(j0 + base + u); found = true; }
        }
        int i = ib * 512 + q * 256 + t;
        float cn = 0.25f * fmaf(ax[q], ax[q], fmaf(ay[q], ay[q], az[q]*az[q]));
        float bf = bd[q] + cn;
        u32 db = __float_as_uint(bf);
        db = (db & 0x80000000u) ? ~db : (db | 0x80000000u);
        atomicMin(&nn[side * 2048 + i], ((u64)db << 32) | bj);
    }
}

// ---------------- fused mask(LDS, per-block) + loss2 + scat1 ----------------
// 16 blocks x 256. Each block recomputes the full 4096-entry mask into LDS.
// Block b scatters gt entries [b*256, b*256+256). Masked flag packed into hash.
__global__ __launch_bounds__(256) void k_msc(
        const u64* __restrict__ nn, const u32* __restrict__ bm,
        const float* __restrict__ spm, const int* __restrict__ gti,
        u32* __restrict__ gtb, u64* __restrict__ hash, float* __restrict__ acc) {
    __shared__ u8 smask[4096];
    __shared__ float red[4];
    const int t = threadIdx.x;
    float c = 0.f;
    for (int e = t; e < 4096; e += 256) {
        int side = e >> 11;
        u32 j = (u32)(nn[e] & 0xFFFFFFFFull);
        u32 bit = (bm[side * BM_WORDS_I + (j >> 5)] >> (j & 31)) & 1u;
        smask[e] = (u8)bit;
        if (blockIdx.x == 0) c += fabsf((1.f - spm[e]) - (float)bit);
    }
    if (blockIdx.x == 0) {
        for (int o = 32; o; o >>= 1) c += __shfl_xor(c, o);
        if ((t & 63) == 0) red[t >> 6] = c;
    }
    __syncthreads();
    if (blockIdx.x == 0 && t == 0) acc[2] = red[0] + red[1] + red[2] + red[3];

    // scat1 slice: one k per thread
    int k = blockIdx.x * 256 + t;
    int xi = gti[2*k], yi = gti[2*k+1];
    u32 cell = (u32)(xi * 2048 + yi);
    u32 masked = (smask[xi] && smask[2048 + yi]) ? 1u : 0u;
    if (masked) atomicOr(&gtb[xi * 64 + (yi >> 5)], 1u << (yi & 31));
    u64 val = ((u64)(cell + 1) << 13) | ((u64)masked << 12) | (u32)k;
    u32 h = (cell * 2654435761u) >> 19;
    while (true) {
        u64 cur = hash[h];
        if (cur == 0ull) cur = atomicCAS(&hash[h], 0ull, val);
        if (cur == 0ull) break;                                   // inserted
        if ((cur >> 13) == (u64)(cell + 1)) { atomicMax(&hash[h], val); break; }
        h = (h + 1) & 8191;
    }
}

// ---------------- scat2: collect masked candidates from hash ----------------
__global__ void k_scat2(const u64* __restrict__ hash, const float* __restrict__ gtv,
                        u64* __restrict__ cand, u32* __restrict__ cnt) {
    int e = blockIdx.x * 256 + threadIdx.x;   // 0..8191
    u64 s = hash[e];
    if (s == 0ull) return;
    if (!((s >> 12) & 1ull)) return;          // masked flag
    u32 cell = (u32)(s >> 13) - 1u;
    u32 k = (u32)(s & 0xFFFull);
    u32 vb = __float_as_uint(gtv[k]);         // overlaps >= 0 -> bits monotonic
    u32 idx = atomicAdd(cnt, 1u);
    cand[idx] = ((u64)vb << 22) | (u32)(0x3FFFFF - cell);
}

// ---------------- top-256 cap, spread over 16 blocks ----------------
__global__ __launch_bounds__(256) void k_top(const u64* __restrict__ cand,
                                             const u32* __restrict__ cnt,
                                             u32* __restrict__ gtb) {
    const int n = (int)cnt[0];
    if (n <= MAXPTS) return;
    if (blockIdx.x * 256 >= n) return;
    __shared__ u64 keys[4096];
    const int t = threadIdx.x;
    for (int e = t; e < n; e += 256) keys[e] = cand[e];
    __syncthreads();
    int c = blockIdx.x * 256 + t;
    if (c >= n) return;
    u64 me = keys[c];
    int rank = 0;
    #pragma unroll 4
    for (int j = 0; j < n; ++j) rank += (keys[j] > me);
    if (rank >= MAXPTS) {
        u32 cell = 0x3FFFFFu - (u32)(me & 0x3FFFFFull);
        int row = cell >> 11, col = cell & 2047;
        atomicAnd(&gtb[row * 64 + (col >> 5)], ~(1u << (col & 31)));
    }
}

// ---------------- circle-loss terms ----------------
__device__ __forceinline__ void circle_terms(float d, bool g, float& lp, float& ln) {
    if (g) { float a = d - 0.1f; lp = a > 0.f ? 24.f*a*a : 0.f; ln = 0.f; }
    else   { float b = 1.4f - d; ln = b > 0.f ? 24.f*b*b : 0.f; lp = 0.f; }
}

__device__ __forceinline__ float softplus_(float x) {
    return fmaxf(x, 0.f) + log1pf(expf(-fabsf(x)));
}

// ---------------- fused MFMA bf16 GEMM + laplace + row/col LSE partials ----------------
__global__ __launch_bounds__(256) void k_gemm(
        const float* __restrict__ A, const float* __restrict__ B,
        const float* __restrict__ spm, const u32* __restrict__ gtb,
        float4* __restrict__ rowp, float4* __restrict__ colp) {
    __shared__ __align__(16) short As[16384];   // 32 KB
    __shared__ __align__(16) short Bs[8192];    // 16 KB
    __shared__ u32 gtw[256];                    // 1 KB: 128 rows x 2 words
    const int t = threadIdx.x;
    const int l = t & 63, wid = t >> 6;
    const int wm = wid >> 1, wn = wid & 1;
    const int i0 = blockIdx.y * 128, j0 = blockIdx.x * 64;

    // stage gt bits for this 128x64 tile (1 u32 per thread, broadcast reads later)
    gtw[t] = gtb[(size_t)(i0 + (t >> 1)) * 64 + (j0 >> 5) + (t & 1)];

    f32x4 acc[4][2] = {};

    for (int ks = 0; ks < 2; ++ks) {
        __syncthreads();
        #pragma unroll
        for (int it = 0; it < 12; ++it) {
            int sl = it * 256 + t;                 // 0..3071 slots of 16B
            int c = sl & 63, q = c >> 4, r15 = c & 15;
            const float* src;
            short* dst;
            int kf;
            if (it < 8) {                          // A: slots 0..2047
                int frag = sl >> 6;                // mf(8) x kf(4)
                kf = frag & 3;
                int row = (frag >> 2) * 16 + r15;
                src = A + (size_t)(i0 + row) * 256;
                dst = &As[sl * 8];
            } else {                               // B: slots 2048..3071
                int sl2 = sl - 2048;
                int frag = sl2 >> 6;               // nf(4) x kf(4)
                kf = frag & 3;
                int row = (frag >> 2) * 16 + r15;
                src = B + (size_t)(j0 + row) * 256;
                dst = &Bs[sl2 * 8];
            }
            int col = ks * 128 + kf * 32 + q * 8;
            float4 v0 = *(const float4*)(src + col);
            float4 v1 = *(const float4*)(src + col + 4);
            u32 w0 = __builtin_amdgcn_perm(__float_as_uint(v0.y), __float_as_uint(v0.x), 0x07060302u);
            u32 w1 = __builtin_amdgcn_perm(__float_as_uint(v0.w), __float_as_uint(v0.z), 0x07060302u);
            u32 w2 = __builtin_amdgcn_perm(__float_as_uint(v1.y), __float_as_uint(v1.x), 0x07060302u);
            u32 w3 = __builtin_amdgcn_perm(__float_as_uint(v1.w), __float_as_uint(v1.z), 0x07060302u);
            *(uint4*)dst = make_uint4(w0, w1, w2, w3);
        }
        __syncthreads();

        #pragma unroll
        for (int kf = 0; kf < 4; ++kf) {
            short8 a[4], b[2];
            #pragma unroll
            for (int mi = 0; mi < 4; ++mi)
                a[mi] = *(const short8*)&As[(((wm*4 + mi)*4 + kf) << 9) + l*8];
            #pragma unroll
            for (int ni = 0; ni < 2; ++ni)
                b[ni] = *(const short8*)&Bs[(((wn*2 + ni)*4 + kf) << 9) + l*8];
            #pragma unroll
            for (int mi = 0; mi < 4; ++mi)
                #pragma unroll
                for (int ni = 0; ni < 2; ++ni)
                    acc[mi][ni] = __builtin_amdgcn_mfma_f32_16x16x32_bf16(
                        a[mi], b[ni], acc[mi][ni], 0, 0, 0);
        }
    }

    // ---- epilogue ----
    // C/D layout: col = lane&15, row = (lane>>4)*4 + reg  [m89-verified]
    const int cq = l >> 4, cr = l & 15;
    const int rows0 = i0 + wm * 64, cols0 = j0 + wn * 32;

    float vmj[2];
    #pragma unroll
    for (int ni = 0; ni < 2; ++ni) vmj[ni] = 1.f - spm[2048 + cols0 + ni*16 + cr];
    float vmi[4][4];
    #pragma unroll
    for (int mi = 0; mi < 4; ++mi)
        #pragma unroll
        for (int rr = 0; rr < 4; ++rr)
            vmi[mi][rr] = 1.f - spm[rows0 + mi*16 + cq*4 + rr];

    // d in place + gt bitmask from LDS bits (bit mi*8 + ni*4 + rr)
    u32 gmask = 0;
    #pragma unroll
    for (int mi = 0; mi < 4; ++mi)
        #pragma unroll
        for (int rr = 0; rr < 4; ++rr) {
            u32 w = gtw[(wm*64 + mi*16 + cq*4 + rr) * 2 + wn];
            #pragma unroll
            for (int ni = 0; ni < 2; ++ni)
                if ((w >> (ni*16 + cr)) & 1u) gmask |= 1u << (mi*8 + ni*4 + rr);
        }
    #pragma unroll
    for (int mi = 0; mi < 4; ++mi)
        #pragma unroll
        for (int ni = 0; ni < 2; ++ni)
            #pragma unroll
            for (int rr = 0; rr < 4; ++rr) {
                float s  = acc[mi][ni][rr];
                float fs = fmaxf(2.f - 2.f*s, 0.f);
                acc[mi][ni][rr] = sqrtf(fs) * expf(0.5f * vmi[mi][rr] * vmj[ni]);
            }

    const int jt2 = blockIdx.x * 2 + wn;   // 0..63
    const int it2 = blockIdx.y * 2 + wm;   // 0..31

    // row-LSE: per row (mi,cq,rr), over ni(2) x 16 lanes. two-phase.
    #pragma unroll
    for (int mi = 0; mi < 4; ++mi)
        #pragma unroll
        for (int rr = 0; rr < 4; ++rr) {
            float lp0, ln0, lp1, ln1;
            circle_terms(acc[mi][0][rr], (gmask >> (mi*8 + rr)) & 1, lp0, ln0);
            circle_terms(acc[mi][1][rr], (gmask >> (mi*8 + 4 + rr)) & 1, lp1, ln1);
            float mp = fmaxf(lp0, lp1), mn = fmaxf(ln0, ln1);
            #pragma unroll
            for (int o = 1; o < 16; o <<= 1) {
                mp = fmaxf(mp, __shfl_xor(mp, o));
                mn = fmaxf(mn, __shfl_xor(mn, o));
            }
            float sp = expf(lp0 - mp) + expf(lp1 - mp);
            float sn = expf(ln0 - mn) + expf(ln1 - mn);
            #pragma unroll
            for (int o = 1; o < 16; o <<= 1) {
                sp += __shfl_xor(sp, o);
                sn += __shfl_xor(sn, o);
            }
            if (cr == mi*4 + rr) {
                int row = rows0 + mi*16 + cq*4 + rr;
                rowp[(size_t)jt2 * 2048 + row] = make_float4(mp, sp, mn, sn);
            }
        }

    // col-LSE: per col (ni,cr), over mi(4) x rr(4) in-lane, then cq bfly.
    #pragma unroll
    for (int ni = 0; ni < 2; ++ni) {
        float lp[16], ln[16];
        #pragma unroll
        for (int mi = 0; mi < 4; ++mi)
            #pragma unroll
            for (int rr = 0; rr < 4; ++rr)
                circle_terms(acc[mi][ni][rr], (gmask >> (mi*8 + ni*4 + rr)) & 1,
                             lp[mi*4+rr], ln[mi*4+rr]);
        float mp = lp[0], mn = ln[0];
        #pragma unroll
        for (int e = 1; e < 16; ++e) { mp = fmaxf(mp, lp[e]); mn = fmaxf(mn, ln[e]); }
        #pragma unroll
        for (int o = 16; o < 64; o <<= 1) {
            mp = fmaxf(mp, __shfl_xor(mp, o));
            mn = fmaxf(mn, __shfl_xor(mn, o));
        }
        float sp = 0.f, sn = 0.f;
        #pragma unroll
        for (int e = 0; e < 16; ++e) { sp += expf(lp[e] - mp); sn += expf(ln[e] - mn); }
        #pragma unroll
        for (int o = 16; o < 64; o <<= 1) {
            sp += __shfl_xor(sp, o);
            sn += __shfl_xor(sn, o);
        }
        if (cq == 0) {
            int col = cols0 + ni*16 + cr;
            colp[(size_t)it2 * 2048 + col] = make_float4(mp, sp, mn, sn);
        }
    }
}

// ---------------- merge partials + finalize (last-block ticket) ----------------
__global__ __launch_bounds__(256) void k_merge(const float4* __restrict__ rowp,
                                               const float4* __restrict__ colp,
                                               float* __restrict__ acc,
                                               u32* __restrict__ cnt,
                                               float* __restrict__ out) {
    const int t = threadIdx.x;
    const int bx = blockIdx.x;  // 0..15: 0-7 rows, 8-15 cols
    float Mp = -1e30f, Sp = 0.f, Mn = -1e30f, Sn = 0.f;
    if (bx < 8) {
        int row = bx * 256 + t;
        for (int jt = 0; jt < 64; ++jt) {
            float4 p = rowp[(size_t)jt * 2048 + row];
            float nm = fmaxf(Mp, p.x); Sp = Sp*expf(Mp-nm) + p.y*expf(p.x-nm); Mp = nm;
            nm = fmaxf(Mn, p.z); Sn = Sn*expf(Mn-nm) + p.w*expf(p.z-nm); Mn = nm;
        }
    } else {
        int col = (bx - 8) * 256 + t;
        for (int it = 0; it < 32; ++it) {
            float4 p = colp[(size_t)it * 2048 + col];
            float nm = fmaxf(Mp, p.x); Sp = Sp*expf(Mp-nm) + p.y*expf(p.x-nm); Mp = nm;
            nm = fmaxf(Mn, p.z); Sn = Sn*expf(Mn-nm) + p.w*expf(p.z-nm); Mn = nm;
        }
    }
    float x = (Mp + logf(Sp)) + (Mn + logf(Sn));
    float lv = softplus_(x) * (1.f / 24.f);
    for (int o = 32; o; o >>= 1) lv += __shfl_xor(lv, o);
    __shared__ float wsum[4];
    __shared__ u32 tic;
    if ((t & 63) == 0) wsum[t >> 6] = lv;
    __syncthreads();
    if (t == 0) {
        atomicAdd(&acc[bx < 8 ? 0 : 1], wsum[0] + wsum[1] + wsum[2] + wsum[3]);
        __threadfence();
        tic = atomicAdd(&cnt[1], 1u);
    }
    __syncthreads();
    if (t == 0 && tic == 15u) {
        __threadfence();
        float a0 = atomicAdd(&acc[0], 0.f);
        float a1 = atomicAdd(&acc[1], 0.f);
        float a2 = atomicAdd(&acc[2], 0.f);
        float l1 = (a0 + a1) * (0.5f / 2048.f);
        float l2 = a2 * (1.f / 4096.f);
        out[0] = l1 + l2; out[1] = l1; out[2] = l2;
    }
}

extern "C" void kernel_launch(void* const* d_in, const int* in_sizes, int n_in,
                              void* d_out, int out_size, void* d_ws, size_t ws_size,
                              hipStream_t stream) {
    (void)in_sizes; (void)n_in; (void)out_size; (void)ws_size;
    const float* ref_points = (const float*)d_in[0];
    const float* src_points = (const float*)d_in[1];
    const float* ref_c      = (const float*)d_in[2];
    const float* src_c      = (const float*)d_in[3];
    const float* ref_f      = (const float*)d_in[4];
    const float* src_f      = (const float*)d_in[5];
    const int*   gti        = (const int*)d_in[6];
    const float* gtv        = (const float*)d_in[7];
    const float* spm        = (const float*)d_in[8];
    const int*   rbi        = (const int*)d_in[9];
    const int*   sbi        = (const int*)d_in[10];

    char* ws = (char*)d_ws;
    float4* rowp = (float4*)(ws + OFF_ROWP);
    float4* colp = (float4*)(ws + OFF_COLP);
    u32*   gtb  = (u32*)  (ws + OFF_GTB);
    u64*   nn   = (u64*)  (ws + OFF_NN);
    u64*   cand = (u64*)  (ws + OFF_CAND);
    float* acc  = (float*)(ws + OFF_ACC);
    u32*   cnt  = (u32*)  (ws + OFF_CNT);
    u32*   bm   = (u32*)  (ws + OFF_BM);
    u64*   hash = (u64*)  (ws + OFF_HASH);

    k_init <<<128, 256, 0, stream>>>((uint4*)gtb, nn, acc, hash, cnt, bm);
    k_bm   <<<(2*NBACK + 255)/256, 256, 0, stream>>>(rbi, sbi, bm);
    k_nn   <<<dim3(512, 2), 256, 0, stream>>>(ref_points, src_points, ref_c, src_c, nn);
    k_msc  <<<16, 256, 0, stream>>>(nn, bm, spm, gti, gtb, hash, acc);
    k_scat2<<<32, 256, 0, stream>>>(hash, gtv, cand, cnt);
    k_top  <<<16, 256, 0, stream>>>(cand, cnt, gtb);
    k_gemm <<<dim3(32, 16), 256, 0, stream>>>(ref_f, src_f, spm, gtb, rowp, colp);
    k_merge<<<16, 256, 0, stream>>>(rowp, colp, acc, cnt, (float*)d_out);
}

// Round 11
// 118.217 us; speedup vs baseline: 1.3752x; 1.0175x over previous
//
#include <hip/hip_runtime.h>
#include <math.h>

using u8  = unsigned char;
using u32 = unsigned int;
using u64 = unsigned long long;

typedef short short8 __attribute__((ext_vector_type(8)));
typedef float f32x4  __attribute__((ext_vector_type(4)));

#define MC 2048
#define NC 2048
#define DF 256
#define NFULL 50000
#define NBACK 30000
#define KCORR 4096
#define MAXPTS 256
#define NN_CHUNK 196   // 256 chunks * 196 = 50176 >= 50000; 49 groups of 4
#define BM_WORDS_I 1568

// ---------------- workspace layout ----------------
constexpr size_t OFF_ROWP = 0;                                // 64*2048 float4 = 2 MB
constexpr size_t OFF_COLP = (size_t)2 * 1024 * 1024;          // 32*2048 float4 = 1 MB
constexpr size_t OFF_GTB  = (size_t)3 * 1024 * 1024;          // 2048*64 u32 = 512 KB (bitfield)
constexpr size_t OFF_NN   = OFF_GTB + (size_t)512 * 1024;     // 4096 u64 = 32 KB
constexpr size_t OFF_CAND = OFF_NN + 4096 * 8;                // 4096 u64 = 32 KB
constexpr size_t OFF_ACC  = OFF_CAND + 4096 * 8;              // 8 f32
constexpr size_t OFF_CNT  = OFF_ACC + 256;                    // cnt, ticket
constexpr size_t OFF_BM   = OFF_CNT + 256;                    // 2*1568 u32 = 12.5 KB
constexpr size_t OFF_HASH = OFF_BM + 3200 * 4;                // 8192 u64 = 64 KB

// ---------------- init: zero gtb/hash/nn/bm/acc/cnt ----------------
__global__ __launch_bounds__(256) void k_init(uint4* __restrict__ gtb4, u64* __restrict__ nn,
                                              float* __restrict__ acc, u64* __restrict__ hash,
                                              u32* __restrict__ cnt, u32* __restrict__ bm) {
    int e = blockIdx.x * 256 + threadIdx.x;   // 0..32767
    gtb4[e] = make_uint4(0u, 0u, 0u, 0u);
    if (e < 8192) hash[e] = 0ull;
    if (e < 4096) nn[e] = ~0ull;
    if (e < 2 * BM_WORDS_I) bm[e] = 0u;
    if (e < 8) acc[e] = 0.f;
    if (e < 2) cnt[e] = 0u;
}

// ---------------- NN argmin: LDS-staged, IPT=4, group-of-4 min + index rescan ----
// grid: x = (2 i-blocks) | (256 chunks << 1), y = side. block 256, IPT=4.
// 1024 blocks -> 4 blocks/CU -> 4 waves/SIMD. Each ds_read_b128 feeds 4 points
// (LDS traffic halved vs IPT=2). Inner loop: min-only tracking (fmin tree +
// winning group id) = 4.5 VALU/eval; exact index recovered by rescanning the
// winning 4-candidate group (bit-identical fma chain -> == match; strict <
// group update + in-order rescan preserves argmin first-index tie-break).
// Prologue: first 235 blocks also build the back-index bitmaps (k_bm folded).
__global__ __launch_bounds__(256) void k_nn(
        const float* __restrict__ fr, const float* __restrict__ fs,
        const float* __restrict__ cr, const float* __restrict__ cs,
        const int* __restrict__ rbi, const int* __restrict__ sbi,
        u32* __restrict__ bm, u64* __restrict__ nn) {
    const int side = blockIdx.y;
    const float* full = side ? fs : fr;
    const float* corr = side ? cs : cr;
    const int ib = blockIdx.x & 1, ch = blockIdx.x >> 1;
    const int t = threadIdx.x;

    // folded k_bm: 235*256 = 60160 >= 60000 entries, overlapped with staging
    int gb = side * 512 + blockIdx.x;
    if (gb < 235) {
        int e = gb * 256 + t;
        if (e < 2 * NBACK) {
            int s2 = e < NBACK ? 0 : 1;
            int v = s2 ? sbi[e - NBACK] : rbi[e];
            atomicOr(&bm[s2 * BM_WORDS_I + (v >> 5)], 1u << (v & 31));
        }
    }

    __shared__ float4 s4[NN_CHUNK];
    const int j0 = ch * NN_CHUNK;
    for (int e = t; e < NN_CHUNK; e += 256) {
        int j = j0 + e;
        float4 v;
        if (j < NFULL) {
            float x = full[j*3], y = full[j*3+1], z = full[j*3+2];
            v = make_float4(x, y, z, x*x + y*y + z*z);
        } else {
            v = make_float4(0.f, 0.f, 0.f, 3.0e38f);   // sentinel: never wins
        }
        s4[e] = v;
    }

    float ax[4], ay[4], az[4], bd[4];
    int bg[4];
    #pragma unroll
    for (int q = 0; q < 4; ++q) {
        int i = ib * 1024 + q * 256 + t;
        float cx = corr[i*3], cy = corr[i*3+1], cz = corr[i*3+2];
        ax[q] = -2.f*cx; ay[q] = -2.f*cy; az[q] = -2.f*cz;
        bd[q] = 3.4e38f; bg[q] = 0;
    }
    __syncthreads();

    #pragma unroll 2
    for (int g = 0; g < 49; ++g) {
        float4 p0 = s4[g*4+0], p1 = s4[g*4+1], p2 = s4[g*4+2], p3 = s4[g*4+3];
        #pragma unroll
        for (int q = 0; q < 4; ++q) {
            float d0 = fmaf(ax[q], p0.x, fmaf(ay[q], p0.y, fmaf(az[q], p0.z, p0.w)));
            float d1 = fmaf(ax[q], p1.x, fmaf(ay[q], p1.y, fmaf(az[q], p1.z, p1.w)));
            float d2 = fmaf(ax[q], p2.x, fmaf(ay[q], p2.y, fmaf(az[q], p2.z, p2.w)));
            float d3 = fmaf(ax[q], p3.x, fmaf(ay[q], p3.y, fmaf(az[q], p3.z, p3.w)));
            float gm = fminf(fminf(d0, d1), fminf(d2, d3));
            bool win = gm < bd[q];
            bd[q] = fminf(bd[q], gm);
            bg[q] = win ? g : bg[q];
        }
    }

    #pragma unroll
    for (int q = 0; q < 4; ++q) {
        // rescan winning group for the exact (first) index
        int base = bg[q] * 4;
        u32 bj = (u32)(j0 + base);
        bool found = false;
        #pragma unroll
        for (int u = 0; u < 4; ++u) {
            float4 p = s4[base + u];
            float d = fmaf(ax[q], p.x, fmaf(ay[q], p.y, fmaf(az[q], p.z, p.w)));
            if (!found && d == bd[q]) { bj = (u32)(j0 + base + u); found = true; }
        }
        int i = ib * 1024 + q * 256 + t;
        float cn = 0.25f * fmaf(ax[q], ax[q], fmaf(ay[q], ay[q], az[q]*az[q]));
        float bf = bd[q] + cn;
        u32 db = __float_as_uint(bf);
        db = (db & 0x80000000u) ? ~db : (db | 0x80000000u);
        atomicMin(&nn[side * 2048 + i], ((u64)db << 32) | bj);
    }
}

// ---------------- fused mask (direct L2 lookups) + loss2 + scat1 ----------------
// 16 blocks x 256; one gt entry per thread; masked derived via nn->bm chain.
__device__ __forceinline__ u32 mask_of(const u64* nn, const u32* bm, int idx, int side) {
    u32 j = (u32)(nn[idx] & 0xFFFFFFFFull);
    return (bm[side * BM_WORDS_I + (j >> 5)] >> (j & 31)) & 1u;
}

__global__ __launch_bounds__(256) void k_msc(
        const u64* __restrict__ nn, const u32* __restrict__ bm,
        const float* __restrict__ spm, const int* __restrict__ gti,
        u32* __restrict__ gtb, u64* __restrict__ hash, float* __restrict__ acc) {
    const int t = threadIdx.x;
    if (blockIdx.x == 0) {
        __shared__ float red[4];
        float c = 0.f;
        for (int e = t; e < 4096; e += 256)
            c += fabsf((1.f - spm[e]) - (float)mask_of(nn, bm, e, e >> 11));
        for (int o = 32; o; o >>= 1) c += __shfl_xor(c, o);
        if ((t & 63) == 0) red[t >> 6] = c;
        __syncthreads();
        if (t == 0) acc[2] = red[0] + red[1] + red[2] + red[3];
    }

    // scat1 slice: one k per thread
    int k = blockIdx.x * 256 + t;
    int xi = gti[2*k], yi = gti[2*k+1];
    u32 cell = (u32)(xi * 2048 + yi);
    u32 masked = mask_of(nn, bm, xi, 0) & mask_of(nn, bm, 2048 + yi, 1);
    if (masked) atomicOr(&gtb[xi * 64 + (yi >> 5)], 1u << (yi & 31));
    u64 val = ((u64)(cell + 1) << 13) | ((u64)masked << 12) | (u32)k;
    u32 h = (cell * 2654435761u) >> 19;
    while (true) {
        u64 cur = hash[h];
        if (cur == 0ull) cur = atomicCAS(&hash[h], 0ull, val);
        if (cur == 0ull) break;                                   // inserted
        if ((cur >> 13) == (u64)(cell + 1)) { atomicMax(&hash[h], val); break; }
        h = (h + 1) & 8191;
    }
}

// ---------------- scat2: collect masked candidates from hash ----------------
__global__ void k_scat2(const u64* __restrict__ hash, const float* __restrict__ gtv,
                        u64* __restrict__ cand, u32* __restrict__ cnt) {
    int e = blockIdx.x * 256 + threadIdx.x;   // 0..8191
    u64 s = hash[e];
    if (s == 0ull) return;
    if (!((s >> 12) & 1ull)) return;          // masked flag
    u32 cell = (u32)(s >> 13) - 1u;
    u32 k = (u32)(s & 0xFFFull);
    u32 vb = __float_as_uint(gtv[k]);         // overlaps >= 0 -> bits monotonic
    u32 idx = atomicAdd(cnt, 1u);
    cand[idx] = ((u64)vb << 22) | (u32)(0x3FFFFF - cell);
}

// ---------------- top-256 cap, spread over 16 blocks ----------------
__global__ __launch_bounds__(256) void k_top(const u64* __restrict__ cand,
                                             const u32* __restrict__ cnt,
                                             u32* __restrict__ gtb) {
    const int n = (int)cnt[0];
    if (n <= MAXPTS) return;
    if (blockIdx.x * 256 >= n) return;
    __shared__ u64 keys[4096];
    const int t = threadIdx.x;
    for (int e = t; e < n; e += 256) keys[e] = cand[e];
    __syncthreads();
    int c = blockIdx.x * 256 + t;
    if (c >= n) return;
    u64 me = keys[c];
    int rank = 0;
    #pragma unroll 4
    for (int j = 0; j < n; ++j) rank += (keys[j] > me);
    if (rank >= MAXPTS) {
        u32 cell = 0x3FFFFFu - (u32)(me & 0x3FFFFFull);
        int row = cell >> 11, col = cell & 2047;
        atomicAnd(&gtb[row * 64 + (col >> 5)], ~(1u << (col & 31)));
    }
}

// ---------------- circle-loss terms ----------------
__device__ __forceinline__ void circle_terms(float d, bool g, float& lp, float& ln) {
    if (g) { float a = d - 0.1f; lp = a > 0.f ? 24.f*a*a : 0.f; ln = 0.f; }
    else   { float b = 1.4f - d; ln = b > 0.f ? 24.f*b*b : 0.f; lp = 0.f; }
}

__device__ __forceinline__ float softplus_(float x) {
    return fmaxf(x, 0.f) + log1pf(expf(-fabsf(x)));
}

// ---------------- fused MFMA bf16 GEMM + laplace + row/col LSE partials ----------------
__global__ __launch_bounds__(256) void k_gemm(
        const float* __restrict__ A, const float* __restrict__ B,
        const float* __restrict__ spm, const u32* __restrict__ gtb,
        float4* __restrict__ rowp, float4* __restrict__ colp) {
    __shared__ __align__(16) short As[16384];   // 32 KB
    __shared__ __align__(16) short Bs[8192];    // 16 KB
    __shared__ u32 gtw[256];                    // 1 KB: 128 rows x 2 words
    const int t = threadIdx.x;
    const int l = t & 63, wid = t >> 6;
    const int wm = wid >> 1, wn = wid & 1;
    const int i0 = blockIdx.y * 128, j0 = blockIdx.x * 64;

    // stage gt bits for this 128x64 tile (1 u32 per thread, broadcast reads later)
    gtw[t] = gtb[(size_t)(i0 + (t >> 1)) * 64 + (j0 >> 5) + (t & 1)];

    f32x4 acc[4][2] = {};

    for (int ks = 0; ks < 2; ++ks) {
        __syncthreads();
        #pragma unroll
        for (int it = 0; it < 12; ++it) {
            int sl = it * 256 + t;                 // 0..3071 slots of 16B
            int c = sl & 63, q = c >> 4, r15 = c & 15;
            const float* src;
            short* dst;
            int kf;
            if (it < 8) {                          // A: slots 0..2047
                int frag = sl >> 6;                // mf(8) x kf(4)
                kf = frag & 3;
                int row = (frag >> 2) * 16 + r15;
                src = A + (size_t)(i0 + row) * 256;
                dst = &As[sl * 8];
            } else {                               // B: slots 2048..3071
                int sl2 = sl - 2048;
                int frag = sl2 >> 6;               // nf(4) x kf(4)
                kf = frag & 3;
                int row = (frag >> 2) * 16 + r15;
                src = B + (size_t)(j0 + row) * 256;
                dst = &Bs[sl2 * 8];
            }
            int col = ks * 128 + kf * 32 + q * 8;
            float4 v0 = *(const float4*)(src + col);
            float4 v1 = *(const float4*)(src + col + 4);
            u32 w0 = __builtin_amdgcn_perm(__float_as_uint(v0.y), __float_as_uint(v0.x), 0x07060302u);
            u32 w1 = __builtin_amdgcn_perm(__float_as_uint(v0.w), __float_as_uint(v0.z), 0x07060302u);
            u32 w2 = __builtin_amdgcn_perm(__float_as_uint(v1.y), __float_as_uint(v1.x), 0x07060302u);
            u32 w3 = __builtin_amdgcn_perm(__float_as_uint(v1.w), __float_as_uint(v1.z), 0x07060302u);
            *(uint4*)dst = make_uint4(w0, w1, w2, w3);
        }
        __syncthreads();

        #pragma unroll
        for (int kf = 0; kf < 4; ++kf) {
            short8 a[4], b[2];
            #pragma unroll
            for (int mi = 0; mi < 4; ++mi)
                a[mi] = *(const short8*)&As[(((wm*4 + mi)*4 + kf) << 9) + l*8];
            #pragma unroll
            for (int ni = 0; ni < 2; ++ni)
                b[ni] = *(const short8*)&Bs[(((wn*2 + ni)*4 + kf) << 9) + l*8];
            #pragma unroll
            for (int mi = 0; mi < 4; ++mi)
                #pragma unroll
                for (int ni = 0; ni < 2; ++ni)
                    acc[mi][ni] = __builtin_amdgcn_mfma_f32_16x16x32_bf16(
                        a[mi], b[ni], acc[mi][ni], 0, 0, 0);
        }
    }

    // ---- epilogue ----
    // C/D layout: col = lane&15, row = (lane>>4)*4 + reg  [m89-verified]
    const int cq = l >> 4, cr = l & 15;
    const int rows0 = i0 + wm * 64, cols0 = j0 + wn * 32;

    float vmj[2];
    #pragma unroll
    for (int ni = 0; ni < 2; ++ni) vmj[ni] = 1.f - spm[2048 + cols0 + ni*16 + cr];
    float vmi[4][4];
    #pragma unroll
    for (int mi = 0; mi < 4; ++mi)
        #pragma unroll
        for (int rr = 0; rr < 4; ++rr)
            vmi[mi][rr] = 1.f - spm[rows0 + mi*16 + cq*4 + rr];

    // d in place + gt bitmask from LDS bits (bit mi*8 + ni*4 + rr)
    u32 gmask = 0;
    #pragma unroll
    for (int mi = 0; mi < 4; ++mi)
        #pragma unroll
        for (int rr = 0; rr < 4; ++rr) {
            u32 w = gtw[(wm*64 + mi*16 + cq*4 + rr) * 2 + wn];
            #pragma unroll
            for (int ni = 0; ni < 2; ++ni)
                if ((w >> (ni*16 + cr)) & 1u) gmask |= 1u << (mi*8 + ni*4 + rr);
        }
    #pragma unroll
    for (int mi = 0; mi < 4; ++mi)
        #pragma unroll
        for (int ni = 0; ni < 2; ++ni)
            #pragma unroll
            for (int rr = 0; rr < 4; ++rr) {
                float s  = acc[mi][ni][rr];
                float fs = fmaxf(2.f - 2.f*s, 0.f);
                acc[mi][ni][rr] = sqrtf(fs) * expf(0.5f * vmi[mi][rr] * vmj[ni]);
            }

    const int jt2 = blockIdx.x * 2 + wn;   // 0..63
    const int it2 = blockIdx.y * 2 + wm;   // 0..31

    // row-LSE: per row (mi,cq,rr), over ni(2) x 16 lanes. two-phase.
    #pragma unroll
    for (int mi = 0; mi < 4; ++mi)
        #pragma unroll
        for (int rr = 0; rr < 4; ++rr) {
            float lp0, ln0, lp1, ln1;
            circle_terms(acc[mi][0][rr], (gmask >> (mi*8 + rr)) & 1, lp0, ln0);
            circle_terms(acc[mi][1][rr], (gmask >> (mi*8 + 4 + rr)) & 1, lp1, ln1);
            float mp = fmaxf(lp0, lp1), mn = fmaxf(ln0, ln1);
            #pragma unroll
            for (int o = 1; o < 16; o <<= 1) {
                mp = fmaxf(mp, __shfl_xor(mp, o));
                mn = fmaxf(mn, __shfl_xor(mn, o));
            }
            float sp = expf(lp0 - mp) + expf(lp1 - mp);
            float sn = expf(ln0 - mn) + expf(ln1 - mn);
            #pragma unroll
            for (int o = 1; o < 16; o <<= 1) {
                sp += __shfl_xor(sp, o);
                sn += __shfl_xor(sn, o);
            }
            if (cr == mi*4 + rr) {
                int row = rows0 + mi*16 + cq*4 + rr;
                rowp[(size_t)jt2 * 2048 + row] = make_float4(mp, sp, mn, sn);
            }
        }

    // col-LSE: per col (ni,cr), over mi(4) x rr(4) in-lane, then cq bfly.
    #pragma unroll
    for (int ni = 0; ni < 2; ++ni) {
        float lp[16], ln[16];
        #pragma unroll
        for (int mi = 0; mi < 4; ++mi)
            #pragma unroll
            for (int rr = 0; rr < 4; ++rr)
                circle_terms(acc[mi][ni][rr], (gmask >> (mi*8 + ni*4 + rr)) & 1,
                             lp[mi*4+rr], ln[mi*4+rr]);
        float mp = lp[0], mn = ln[0];
        #pragma unroll
        for (int e = 1; e < 16; ++e) { mp = fmaxf(mp, lp[e]); mn = fmaxf(mn, ln[e]); }
        #pragma unroll
        for (int o = 16; o < 64; o <<= 1) {
            mp = fmaxf(mp, __shfl_xor(mp, o));
            mn = fmaxf(mn, __shfl_xor(mn, o));
        }
        float sp = 0.f, sn = 0.f;
        #pragma unroll
        for (int e = 0; e < 16; ++e) { sp += expf(lp[e] - mp); sn += expf(ln[e] - mn); }
        #pragma unroll
        for (int o = 16; o < 64; o <<= 1) {
            sp += __shfl_xor(sp, o);
            sn += __shfl_xor(sn, o);
        }
        if (cq == 0) {
            int col = cols0 + ni*16 + cr;
            colp[(size_t)it2 * 2048 + col] = make_float4(mp, sp, mn, sn);
        }
    }
}

// ---------------- merge partials + finalize (last-block ticket) ----------------
__global__ __launch_bounds__(256) void k_merge(const float4* __restrict__ rowp,
                                               const float4* __restrict__ colp,
                                               float* __restrict__ acc,
                                               u32* __restrict__ cnt,
                                               float* __restrict__ out) {
    const int t = threadIdx.x;
    const int bx = blockIdx.x;  // 0..15: 0-7 rows, 8-15 cols
    float Mp = -1e30f, Sp = 0.f, Mn = -1e30f, Sn = 0.f;
    if (bx < 8) {
        int row = bx * 256 + t;
        for (int jt = 0; jt < 64; ++jt) {
            float4 p = rowp[(size_t)jt * 2048 + row];
            float nm = fmaxf(Mp, p.x); Sp = Sp*expf(Mp-nm) + p.y*expf(p.x-nm); Mp = nm;
            nm = fmaxf(Mn, p.z); Sn = Sn*expf(Mn-nm) + p.w*expf(p.z-nm); Mn = nm;
        }
    } else {
        int col = (bx - 8) * 256 + t;
        for (int it = 0; it < 32; ++it) {
            float4 p = colp[(size_t)it * 2048 + col];
            float nm = fmaxf(Mp, p.x); Sp = Sp*expf(Mp-nm) + p.y*expf(p.x-nm); Mp = nm;
            nm = fmaxf(Mn, p.z); Sn = Sn*expf(Mn-nm) + p.w*expf(p.z-nm); Mn = nm;
        }
    }
    float x = (Mp + logf(Sp)) + (Mn + logf(Sn));
    float lv = softplus_(x) * (1.f / 24.f);
    for (int o = 32; o; o >>= 1) lv += __shfl_xor(lv, o);
    __shared__ float wsum[4];
    __shared__ u32 tic;
    if ((t & 63) == 0) wsum[t >> 6] = lv;
    __syncthreads();
    if (t == 0) {
        atomicAdd(&acc[bx < 8 ? 0 : 1], wsum[0] + wsum[1] + wsum[2] + wsum[3]);
        __threadfence();
        tic = atomicAdd(&cnt[1], 1u);
    }
    __syncthreads();
    if (t == 0 && tic == 15u) {
        __threadfence();
        float a0 = atomicAdd(&acc[0], 0.f);
        float a1 = atomicAdd(&acc[1], 0.f);
        float a2 = atomicAdd(&acc[2], 0.f);
        float l1 = (a0 + a1) * (0.5f / 2048.f);
        float l2 = a2 * (1.f / 4096.f);
        out[0] = l1 + l2; out[1] = l1; out[2] = l2;
    }
}

extern "C" void kernel_launch(void* const* d_in, const int* in_sizes, int n_in,
                              void* d_out, int out_size, void* d_ws, size_t ws_size,
                              hipStream_t stream) {
    (void)in_sizes; (void)n_in; (void)out_size; (void)ws_size;
    const float* ref_points = (const float*)d_in[0];
    const float* src_points = (const float*)d_in[1];
    const float* ref_c      = (const float*)d_in[2];
    const float* src_c      = (const float*)d_in[3];
    const float* ref_f      = (const float*)d_in[4];
    const float* src_f      = (const float*)d_in[5];
    const int*   gti        = (const int*)d_in[6];
    const float* gtv        = (const float*)d_in[7];
    const float* spm        = (const float*)d_in[8];
    const int*   rbi        = (const int*)d_in[9];
    const int*   sbi        = (const int*)d_in[10];

    char* ws = (char*)d_ws;
    float4* rowp = (float4*)(ws + OFF_ROWP);
    float4* colp = (float4*)(ws + OFF_COLP);
    u32*   gtb  = (u32*)  (ws + OFF_GTB);
    u64*   nn   = (u64*)  (ws + OFF_NN);
    u64*   cand = (u64*)  (ws + OFF_CAND);
    float* acc  = (float*)(ws + OFF_ACC);
    u32*   cnt  = (u32*)  (ws + OFF_CNT);
    u32*   bm   = (u32*)  (ws + OFF_BM);
    u64*   hash = (u64*)  (ws + OFF_HASH);

    k_init <<<128, 256, 0, stream>>>((uint4*)gtb, nn, acc, hash, cnt, bm);
    k_nn   <<<dim3(512, 2), 256, 0, stream>>>(ref_points, src_points, ref_c, src_c,
                                              rbi, sbi, bm, nn);
    k_msc  <<<16, 256, 0, stream>>>(nn, bm, spm, gti, gtb, hash, acc);
    k_scat2<<<32, 256, 0, stream>>>(hash, gtv, cand, cnt);
    k_top  <<<16, 256, 0, stream>>>(cand, cnt, gtb);
    k_gemm <<<dim3(32, 16), 256, 0, stream>>>(ref_f, src_f, spm, gtb, rowp, colp);
    k_merge<<<16, 256, 0, stream>>>(rowp, colp, acc, cnt, (float*)d_out);
}